// Round 11
// baseline (408.356 us; speedup 1.0000x reference)
//
#include <hip/hip_runtime.h>

#define BS 8
#define LQ 900
#define NH 8
#define NL 4
#define NP 4
#define HD 32
#define ED 256
#define LEN_V 21760

#define QB 32        // queries per sample block
#define QCHUNKS 29   // ceil(900/32)

typedef __attribute__((ext_vector_type(8))) short bf16x8;
typedef __attribute__((ext_vector_type(4))) float f32x4;
typedef __attribute__((ext_vector_type(4))) float fv4;

static __device__ __forceinline__ unsigned short f2bf(float f) {
  union { float f; unsigned u; } x; x.f = f;
  unsigned r = x.u + 0x7fffu + ((x.u >> 16) & 1u);
  return (unsigned short)(r >> 16);
}
static __device__ __forceinline__ float bf_lo(unsigned u) {
  union { unsigned u; float f; } x; x.u = u << 16;
  return x.f;
}
static __device__ __forceinline__ float bf_hi(unsigned u) {
  union { unsigned u; float f; } x; x.u = u & 0xffff0000u;
  return x.f;
}
static __device__ __forceinline__ unsigned pack2(float a, float b) {
  return (unsigned)f2bf(a) | ((unsigned)f2bf(b) << 16);
}

// ---------------------------------------------------------------------------
// K0: pre-swizzle w_value (256x256 fp32, [k][n]) into bf16 B-fragment chunks
// ---------------------------------------------------------------------------
__global__ __launch_bounds__(256) void bprep_kernel(
    const float* __restrict__ w, unsigned short* __restrict__ Bsw) {
  const int id = blockIdx.x * 256 + threadIdx.x;   // 8192 threads
  const int n = id & 255;
  const int kseg = (id >> 8) & 3;
  const int kc = id >> 10;
  const float* src = &w[(kc * 32 + kseg * 8) * 256 + n];
  float f[8];
#pragma unroll
  for (int j = 0; j < 8; j++) f[j] = src[j * 256];
  uint4 pk;
  pk.x = pack2(f[0], f[1]);
  pk.y = pack2(f[2], f[3]);
  pk.z = pack2(f[4], f[5]);
  pk.w = pack2(f[6], f[7]);
  *(uint4*)&Bsw[((kc * 4 + kseg) * 256 + n) * 8] = pk;
}

// ---------------------------------------------------------------------------
// K1: v = value @ w_value + b_value (bf16 MFMA) — round-2 version (best
// measured total). Output permuted [b][h][s][d] bf16.
// ---------------------------------------------------------------------------
__global__ __launch_bounds__(256, 4) void vproj_kernel(
    const float* __restrict__ value, const unsigned short* __restrict__ Bsw,
    const float* __restrict__ bias, unsigned short* __restrict__ vout) {
  const int t = threadIdx.x;
  const int row0 = blockIdx.x * 64;
  const int wv = t >> 6;
  const int lane = t & 63;
  const int quad = lane >> 4;
  const int nn = lane & 15;

  __shared__ unsigned short a_lds[4 * 64 * 8];   // [kseg][row][8] 16B chunks, 4 KB

  f32x4 acc[4][4];
#pragma unroll
  for (int i = 0; i < 4; i++)
#pragma unroll
    for (int j = 0; j < 4; j++) acc[i][j] = (f32x4)(0.f);

  const int arow = t >> 2;        // 0..63
  const int akseg = t & 3;        // 0..3
  const unsigned short* bptr = &Bsw[(quad * 256 + wv * 64 + nn) * 8];

  for (int kc = 0; kc < 8; kc++) {
    __syncthreads();
    {
      const float* pa = &value[(row0 + arow) * 256 + kc * 32 + akseg * 8];
      fv4 v0 = __builtin_nontemporal_load((const fv4*)pa);
      fv4 v1 = __builtin_nontemporal_load((const fv4*)(pa + 4));
      uint4 pk;
      pk.x = pack2(v0.x, v0.y);
      pk.y = pack2(v0.z, v0.w);
      pk.z = pack2(v1.x, v1.y);
      pk.w = pack2(v1.z, v1.w);
      *(uint4*)&a_lds[(akseg * 64 + arow) * 8] = pk;
    }
    __syncthreads();

    bf16x8 af[4], bfr[4];
#pragma unroll
    for (int ct = 0; ct < 4; ct++)
      bfr[ct] = *(const bf16x8*)(bptr + (kc * 1024 + ct * 16) * 8);
#pragma unroll
    for (int rt = 0; rt < 4; rt++)
      af[rt] = *(const bf16x8*)&a_lds[(quad * 64 + rt * 16 + nn) * 8];
#pragma unroll
    for (int rt = 0; rt < 4; rt++)
#pragma unroll
      for (int ct = 0; ct < 4; ct++)
        acc[rt][ct] = __builtin_amdgcn_mfma_f32_16x16x32_bf16(
            af[rt], bfr[ct], acc[rt][ct], 0, 0, 0);
  }

  const int bb = row0 / LEN_V;
  const int s0 = row0 - bb * LEN_V;
#pragma unroll
  for (int ct = 0; ct < 4; ct++) {
    const int col = wv * 64 + ct * 16 + nn;
    const float bv = bias[col];
    const int h = col >> 5;
    const int d = col & 31;
    unsigned short* vb = &vout[((bb * NH + h) * LEN_V + s0) * HD + d];
#pragma unroll
    for (int rt = 0; rt < 4; rt++) {
      f32x4 f = acc[rt][ct];
#pragma unroll
      for (int reg = 0; reg < 4; reg++) {
        const int s = rt * 16 + quad * 4 + reg;
        vb[s * HD] = f2bf(f[reg] + bv);
      }
    }
  }
}

// ---------------------------------------------------------------------------
// K23: MERGED projection + softmax + sampling. Phase C = uint4 gathers
// (halves the ~50us VMEM issue floor) + transposed tables (conflict-free
// reads) + shfl merge + STATIC epilogue select. The rounds-8/9 spills came
// from the FULLY-unrolled lp loop keeping 8x16 load VGPRs in flight against
// the 64-VGPR budget; #pragma unroll 2 caps the window at 32 regs (same as
// the proven round-6 uint2 window).
// ---------------------------------------------------------------------------
__global__ __launch_bounds__(256, 4) void samp_kernel(
    const float* __restrict__ query, const float* __restrict__ refp,
    const unsigned short* __restrict__ vp,
    const float* __restrict__ w_off, const float* __restrict__ b_off,
    const float* __restrict__ w_attn, const float* __restrict__ b_attn,
    float* __restrict__ RES) {
  const int t = threadIdx.x;
  const int work = (blockIdx.x & 7) * (8 * QCHUNKS) + (blockIdx.x >> 3);
  const int pair = work / QCHUNKS;          // 0..63, b-major
  const int qc   = work - pair * QCHUNKS;   // 0..28
  const int b = pair >> 3;
  const int h = pair & 7;
  const int q0 = qc * QB;

  __shared__ __align__(16) unsigned char smem[39936];
  float* q_ldsf = (float*)smem;                                  // [32][256], 32KB (dead after proj)
  int   (*soffT)[32][4] = (int(*)[32][4])smem;                   // [16][32][4], aliases q_lds[0..8KB)
  float (*swtT)[32][4]  = (float(*)[32][4])(smem + 8192);        // [16][32][4], aliases q_lds[8..16KB)
  float (*off_lds)[32] = (float(*)[32])(smem + 32768);           // [32][32], 4KB
  float (*aw_lds)[16]  = (float(*)[16])(smem + 32768 + 4096);    // [32][16], 2KB
  float (*ref_lds)[4][2] = (float(*)[4][2])(smem + 32768 + 6144);// [32][4][2], 1KB

  // ---- stage: 32 query rows (float4-coalesced) + reference points ----
#pragma unroll
  for (int k = 0; k < 8; k++) {
    const int f = t + k * 256;
    const int row = f >> 6;
    const int c4i = (f & 63) << 2;
    float4 v = (q0 + row < LQ)
        ? *(const float4*)&query[(b * LQ + q0 + row) * 256 + c4i]
        : make_float4(0.f, 0.f, 0.f, 0.f);
    *(float4*)&q_ldsf[row * 256 + c4i] = v;
  }
  {
    const int q = t >> 3, l = (t >> 1) & 3, xy = t & 1;
    ref_lds[q][l][xy] = (q0 + q < LQ)
        ? refp[((b * LQ + q0 + q) * NL + l) * 2 + xy] : 0.5f;
  }
  __syncthreads();

  // ---- phase P: project this block's 48 cols (32 OFF + 16 LOG) ----
  if (t < 192) {
    const int rg = t / 12;
    const int c4 = t % 12;
    const int col = c4 * 4;                 // 0..44
    const bool isOff = col < 32;
    const float* wbase = isOff ? (w_off + h * 32 + col)
                               : (w_attn + h * 16 + (col - 32));
    const int wstride = isOff ? 256 : 128;
    const float* bb = isOff ? (b_off + h * 32 + col)
                            : (b_attn + h * 16 + (col - 32));

    float4 acc[2];
    acc[0] = make_float4(0.f, 0.f, 0.f, 0.f);
    acc[1] = make_float4(0.f, 0.f, 0.f, 0.f);

    for (int k0 = 0; k0 < 256; k0 += 8) {
      float4 wr[8];
#pragma unroll
      for (int k = 0; k < 8; k++)
        wr[k] = *(const float4*)&wbase[(k0 + k) * wstride];
#pragma unroll
      for (int r = 0; r < 2; r++) {
        const float* ar = &q_ldsf[(rg * 2 + r) * 256 + k0];
        float4 a0 = *(const float4*)&ar[0];
        float4 a1 = *(const float4*)&ar[4];
        float4 s = acc[r];
        s.x += a0.x*wr[0].x + a0.y*wr[1].x + a0.z*wr[2].x + a0.w*wr[3].x
             + a1.x*wr[4].x + a1.y*wr[5].x + a1.z*wr[6].x + a1.w*wr[7].x;
        s.y += a0.x*wr[0].y + a0.y*wr[1].y + a0.z*wr[2].y + a0.w*wr[3].y
             + a1.x*wr[4].y + a1.y*wr[5].y + a1.z*wr[6].y + a1.w*wr[7].y;
        s.z += a0.x*wr[0].z + a0.y*wr[1].z + a0.z*wr[2].z + a0.w*wr[3].z
             + a1.x*wr[4].z + a1.y*wr[5].z + a1.z*wr[6].z + a1.w*wr[7].z;
        s.w += a0.x*wr[0].w + a0.y*wr[1].w + a0.z*wr[2].w + a0.w*wr[3].w
             + a1.x*wr[4].w + a1.y*wr[5].w + a1.z*wr[6].w + a1.w*wr[7].w;
        acc[r] = s;
      }
    }

    const float4 bv = *(const float4*)bb;
#pragma unroll
    for (int r = 0; r < 2; r++) {
      const int q = rg * 2 + r;
      float4 o = make_float4(acc[r].x + bv.x, acc[r].y + bv.y,
                             acc[r].z + bv.z, acc[r].w + bv.w);
      if (isOff) *(float4*)&off_lds[q][col] = o;
      else       *(float4*)&aw_lds[q][col - 32] = o;
    }
  }
  __syncthreads();

  // ---- softmax over the 16 (l,p) logits per query ----
  if (t < QB) {
    float* a = &aw_lds[t][0];
    float m = a[0];
#pragma unroll
    for (int i = 1; i < 16; i++) m = fmaxf(m, a[i]);
    float e[16];
    float ssum = 0.f;
#pragma unroll
    for (int i = 0; i < 16; i++) { e[i] = __expf(a[i] - m); ssum += e[i]; }
    const float inv = 1.f / ssum;
#pragma unroll
    for (int i = 0; i < 16; i++) a[i] = e[i] * inv;
  }
  __syncthreads();

  // ---- phase B: 512 (q,l,p) sets -> transposed corner tables ----
#pragma unroll
  for (int ss = 0; ss < 2; ss++) {
    const int sid = t + ss * 256;
    const int p = sid & 3, l = (sid >> 2) & 3, q = sid >> 4;
    const int lp = sid & 15;
    const int W = 128 >> l;
    const int base = (l == 0) ? 0 : ((l == 1) ? 16384 : ((l == 2) ? 20480 : 21504));
    const float Wf = (float)W;
    const float refx = ref_lds[q][l][0];
    const float refy = ref_lds[q][l][1];
    const float offx = off_lds[q][l * 8 + p * 2 + 0];
    const float offy = off_lds[q][l * 8 + p * 2 + 1];
    const float aw = aw_lds[q][l * 4 + p];
    const float px = refx * Wf + offx - 0.5f;
    const float py = refy * Wf + offy - 0.5f;
    const float x0f = floorf(px), y0f = floorf(py);
    const float dx = px - x0f, dy = py - y0f;
    const int x0 = (int)x0f, y0 = (int)y0f;
    const int x1 = x0 + 1, y1 = y0 + 1;
    const float mx0 = (x0 >= 0 && x0 < W) ? 1.f : 0.f;
    const float mx1 = (x1 >= 0 && x1 < W) ? 1.f : 0.f;
    const float my0 = (y0 >= 0 && y0 < W) ? 1.f : 0.f;
    const float my1 = (y1 >= 0 && y1 < W) ? 1.f : 0.f;
    const int x0c = min(max(x0, 0), W - 1);
    const int x1c = min(max(x1, 0), W - 1);
    const int y0c = min(max(y0, 0), W - 1);
    const int y1c = min(max(y1, 0), W - 1);
    soffT[lp][q][0] = (base + y0c * W + x0c) * 4;   // uint4 units (32 bf16 = 4 uint4)
    soffT[lp][q][1] = (base + y0c * W + x1c) * 4;
    soffT[lp][q][2] = (base + y1c * W + x0c) * 4;
    soffT[lp][q][3] = (base + y1c * W + x1c) * 4;
    swtT[lp][q][0] = (1.f - dx) * (1.f - dy) * mx0 * my0 * aw;
    swtT[lp][q][1] = dx * (1.f - dy) * mx1 * my0 * aw;
    swtT[lp][q][2] = (1.f - dx) * dy * mx0 * my1 * aw;
    swtT[lp][q][3] = dx * dy * mx1 * my1 * aw;
  }
  __syncthreads();

  // ---- phase C: thread = (q, d8, lphalf); 32 uint4 gathers + shfl merge.
  //      unroll 2 caps the in-flight load window at 2x16 VGPRs (no spill).
  {
    const int q = t >> 3;             // 0..31
    const int d8 = (t >> 1) & 3;      // 8 dims: d8*8 .. d8*8+7
    const int lh = t & 1;             // lp half: 0 -> lp 0..7, 1 -> lp 8..15
    const uint4* vpu4 = (const uint4*)vp + (size_t)(b * NH + h) * (LEN_V * HD / 8);
    float r0 = 0.f, r1 = 0.f, r2 = 0.f, r3 = 0.f;
    float r4 = 0.f, r5 = 0.f, r6 = 0.f, r7 = 0.f;
    const int lp0 = lh * 8;
#pragma unroll 2
    for (int i = 0; i < 8; i++) {
      const int lp = lp0 + i;
      const int4 o = *(const int4*)&soffT[lp][q][0];
      const float4 w = *(const float4*)&swtT[lp][q][0];
      const uint4 u00 = vpu4[o.x + d8];
      const uint4 u10 = vpu4[o.y + d8];
      const uint4 u01 = vpu4[o.z + d8];
      const uint4 u11 = vpu4[o.w + d8];
      r0 += w.x * bf_lo(u00.x) + w.y * bf_lo(u10.x) + w.z * bf_lo(u01.x) + w.w * bf_lo(u11.x);
      r1 += w.x * bf_hi(u00.x) + w.y * bf_hi(u10.x) + w.z * bf_hi(u01.x) + w.w * bf_hi(u11.x);
      r2 += w.x * bf_lo(u00.y) + w.y * bf_lo(u10.y) + w.z * bf_lo(u01.y) + w.w * bf_lo(u11.y);
      r3 += w.x * bf_hi(u00.y) + w.y * bf_hi(u10.y) + w.z * bf_hi(u01.y) + w.w * bf_hi(u11.y);
      r4 += w.x * bf_lo(u00.z) + w.y * bf_lo(u10.z) + w.z * bf_lo(u01.z) + w.w * bf_lo(u11.z);
      r5 += w.x * bf_hi(u00.z) + w.y * bf_hi(u10.z) + w.z * bf_hi(u01.z) + w.w * bf_hi(u11.z);
      r6 += w.x * bf_lo(u00.w) + w.y * bf_lo(u10.w) + w.z * bf_lo(u01.w) + w.w * bf_lo(u11.w);
      r7 += w.x * bf_hi(u00.w) + w.y * bf_hi(u10.w) + w.z * bf_hi(u01.w) + w.w * bf_hi(u11.w);
    }
    // merge the two lp-halves across adjacent lanes (lh bit = lane bit 0)
    r0 += __shfl_xor(r0, 1);
    r1 += __shfl_xor(r1, 1);
    r2 += __shfl_xor(r2, 1);
    r3 += __shfl_xor(r3, 1);
    r4 += __shfl_xor(r4, 1);
    r5 += __shfl_xor(r5, 1);
    r6 += __shfl_xor(r6, 1);
    r7 += __shfl_xor(r7, 1);
    if (q0 + q < LQ) {
      float4 rr = lh ? make_float4(r4, r5, r6, r7)
                     : make_float4(r0, r1, r2, r3);
      *(float4*)&RES[(b * LQ + q0 + q) * 256 + h * 32 + d8 * 8 + lh * 4] = rr;
    }
  }
}

// ---------------------------------------------------------------------------
// K4: out = RES @ w_out + b_out. 16 rows x 128 cols per block, 900 blocks.
// ---------------------------------------------------------------------------
__global__ __launch_bounds__(256, 4) void outproj_kernel(
    const float* __restrict__ RES, const float* __restrict__ w,
    const float* __restrict__ bias, float* __restrict__ out) {
  const int t = threadIdx.x;
  const int rc = blockIdx.x >> 1;          // 0..449 row-chunk
  const int ch = blockIdx.x & 1;           // col half
  const int row0 = rc * 16;
  const int rg = t >> 5;                   // 0..7 rowgroups (2 rows each)
  const int c4 = t & 31;                   // 32 col-quads = 128 cols
  const int c0 = ch * 128 + c4 * 4;
  __shared__ float a_lds[16][8];

  float4 acc[2];
  acc[0] = make_float4(0.f, 0.f, 0.f, 0.f);
  acc[1] = make_float4(0.f, 0.f, 0.f, 0.f);

  const int lr = t >> 3;                   // 0..31 (only t<128 stage)
  const int lk = t & 7;
  for (int k0 = 0; k0 < 256; k0 += 8) {
    __syncthreads();
    if (t < 128) a_lds[lr][lk] = RES[(row0 + lr) * 256 + k0 + lk];
    __syncthreads();
    float4 wr[8];
#pragma unroll
    for (int k = 0; k < 8; k++)
      wr[k] = *(const float4*)&w[(k0 + k) * 256 + c0];
#pragma unroll
    for (int r = 0; r < 2; r++) {
      const float* ar = &a_lds[rg * 2 + r][0];
      float4 a0 = *(const float4*)&ar[0];
      float4 a1 = *(const float4*)&ar[4];
      float4 s = acc[r];
      s.x += a0.x*wr[0].x + a0.y*wr[1].x + a0.z*wr[2].x + a0.w*wr[3].x
           + a1.x*wr[4].x + a1.y*wr[5].x + a1.z*wr[6].x + a1.w*wr[7].x;
      s.y += a0.x*wr[0].y + a0.y*wr[1].y + a0.z*wr[2].y + a0.w*wr[3].y
           + a1.x*wr[4].y + a1.y*wr[5].y + a1.z*wr[6].y + a1.w*wr[7].y;
      s.z += a0.x*wr[0].z + a0.y*wr[1].z + a0.z*wr[2].z + a0.w*wr[3].z
           + a1.x*wr[4].z + a1.y*wr[5].z + a1.z*wr[6].z + a1.w*wr[7].z;
      s.w += a0.x*wr[0].w + a0.y*wr[1].w + a0.z*wr[2].w + a0.w*wr[3].w
           + a1.x*wr[4].w + a1.y*wr[5].w + a1.z*wr[6].w + a1.w*wr[7].w;
      acc[r] = s;
    }
  }

  const float4 bv = *(const float4*)&bias[c0];
#pragma unroll
  for (int r = 0; r < 2; r++) {
    const int grow = row0 + rg * 2 + r;
    float4 o = make_float4(acc[r].x + bv.x, acc[r].y + bv.y,
                           acc[r].z + bv.z, acc[r].w + bv.w);
    *(float4*)&out[grow * 256 + c0] = o;
  }
}

extern "C" void kernel_launch(void* const* d_in, const int* in_sizes, int n_in,
                              void* d_out, int out_size, void* d_ws, size_t ws_size,
                              hipStream_t stream) {
  (void)in_sizes; (void)n_in; (void)out_size; (void)ws_size;
  const float* query   = (const float*)d_in[0];
  const float* refp    = (const float*)d_in[1];
  const float* value   = (const float*)d_in[2];
  const float* w_value = (const float*)d_in[3];
  const float* b_value = (const float*)d_in[4];
  const float* w_off   = (const float*)d_in[5];
  const float* b_off   = (const float*)d_in[6];
  const float* w_attn  = (const float*)d_in[7];
  const float* b_attn  = (const float*)d_in[8];
  const float* w_out   = (const float*)d_in[9];
  const float* b_out   = (const float*)d_in[10];
  float* out = (float*)d_out;

  char* ws = (char*)d_ws;
  unsigned short* vp  = (unsigned short*)ws;                    // 89,128,960 B
  float* RES          = (float*)(ws + 89128960);                // 7,372,800 B
  unsigned short* Bsw = (unsigned short*)(ws + 89128960 + 7372800); // 131,072 B

  bprep_kernel<<<32, 256, 0, stream>>>(w_value, Bsw);
  vproj_kernel<<<(BS * LEN_V) / 64, 256, 0, stream>>>(value, Bsw, b_value, vp);
  samp_kernel<<<64 * QCHUNKS, 256, 0, stream>>>(query, refp, vp,
                                                w_off, b_off, w_attn, b_attn,
                                                RES);
  outproj_kernel<<<(BS * LQ) / 16 * 2, 256, 0, stream>>>(RES, w_out, b_out, out);
}